// Round 12
// baseline (354.119 us; speedup 1.0000x reference)
//
#include <hip/hip_runtime.h>
#include <hip/hip_bf16.h>
#include <hip/hip_fp16.h>
#include <math.h>

// ---------------------------------------------------------------------------
// GCN 3-layer + mean-pool + linear head + softmax, fp32 in/out.
// Padded-bucket adjacency (64 slots/node, self-loop slot 0), built with a
// chunk-pipelined counting sort:
//   D1: count(edges A) ∥ layer-1 GEMM (fp32 features read directly, unscaled)
//   D2: count(edges B) ∥ fill(A)   [A's slots final after D1]
//   D3: fill(B)
// Gather1 applies per-edge dinv=rsqrt(cnt+1); layers 2/3 GEMM fold dinv in.
// fp16 pipeline, MFMA v_mfma_f32_16x16x32_f16, fp32 accum.
// ---------------------------------------------------------------------------

#define F 64
#define NGRAPHS 128
#define NCLASSES 10
#define FCAT 192
#define PSPLIT 16
#define CAP 64            // slots per node (deg+1; Poisson(16) -> safe)

typedef _Float16 f16x8 __attribute__((ext_vector_type(8)));
typedef float f32x4 __attribute__((ext_vector_type(4)));

// ---- prep: cnt=0, self-loop meta, W->Wt fp16 transposed -------------------
__global__ void k_prep(const float* __restrict__ W1, const float* __restrict__ W2,
                       const float* __restrict__ W3,
                       int* __restrict__ cnt, int* __restrict__ meta,
                       __half* __restrict__ Wt, int n) {
    int tid = blockIdx.x * blockDim.x + threadIdx.x;
    int stride = gridDim.x * blockDim.x;
    for (int i = tid; i < n; i += stride) {
        cnt[i] = 0;
        meta[(size_t)i << 6] = i;          // self-loop at slot 0
    }
    for (int t = tid; t < 3 * 4096; t += stride) {
        int w = t >> 12, idx = t & 4095;
        int c = idx >> 6, k = idx & 63;
        const float* W = (w == 0) ? W1 : (w == 1) ? W2 : W3;
        Wt[t] = __float2half(W[k * F + c]);
    }
}

// ---- build: [0,gemmBlocks) layer-1 GEMM from fp32 features (unscaled);
//             next cntBlocks: atomic count chunk; rest: pure-write fill chunk
__global__ __launch_bounds__(256) void k_build(
        const int* __restrict__ row, const int* __restrict__ col,
        int* __restrict__ slot, int* __restrict__ cnt, int* __restrict__ meta,
        const float* __restrict__ features, const __half* __restrict__ Wt,
        __half* __restrict__ xwh, int n,
        int gemmBlocks, int cntStart, int cntCount, int fillStart, int fillCount) {
    int b = blockIdx.x;
    if (b >= gemmBlocks) {
        b -= gemmBlocks;
        int cntBlocks = (cntCount + 255) >> 8;
        if (b < cntBlocks) {
            int e = b * 256 + threadIdx.x;
            if (e < cntCount) {
                e += cntStart;
                slot[e] = atomicAdd(&cnt[col[e]], 1);
            }
        } else {
            int e = (b - cntBlocks) * 256 + threadIdx.x;
            if (e < fillCount) {
                e += fillStart;
                meta[((size_t)col[e] << 6) + 1 + slot[e]] = row[e];
            }
        }
        return;
    }
    // ---- layer-1 GEMM tile (16 rows), fp32 features -> fp16 frags ----
    int wid = (int)((b * 256 + threadIdx.x) >> 6);
    int lane = threadIdx.x & 63;
    int r0 = wid * 16;
    if (r0 >= n) return;
    int rA = min(r0 + (lane & 15), n - 1);
    int kOff = (lane >> 4) * 8;
    const float4* xp = (const float4*)(features + (size_t)rA * F + kOff);
    float4 fa = xp[0], fb = xp[1];     // k = kOff..kOff+7
    float4 fc = xp[8], fd = xp[9];     // k = kOff+32..kOff+39
    f16x8 a0 = {(_Float16)fa.x, (_Float16)fa.y, (_Float16)fa.z, (_Float16)fa.w,
                (_Float16)fb.x, (_Float16)fb.y, (_Float16)fb.z, (_Float16)fb.w};
    f16x8 a1 = {(_Float16)fc.x, (_Float16)fc.y, (_Float16)fc.z, (_Float16)fc.w,
                (_Float16)fd.x, (_Float16)fd.y, (_Float16)fd.z, (_Float16)fd.w};
    f32x4 acc0, acc1, acc2, acc3;
#define DO_CT(CT, ACC) { \
        const f16x8* bp = (const f16x8*)(Wt + (((CT) * 16 + (lane & 15)) << 6) + kOff); \
        f16x8 b0 = bp[0], b1 = bp[4]; \
        f32x4 c = {0.f, 0.f, 0.f, 0.f}; \
        c = __builtin_amdgcn_mfma_f32_16x16x32_f16(a0, b0, c, 0, 0, 0); \
        c = __builtin_amdgcn_mfma_f32_16x16x32_f16(a1, b1, c, 0, 0, 0); \
        ACC = c; }
    DO_CT(0, acc0) DO_CT(1, acc1) DO_CT(2, acc2) DO_CT(3, acc3)
#undef DO_CT
    int rBase = r0 + ((lane >> 4) << 2);
    int cl = lane & 15;
#define ST_CT(CT, ACC) { \
        __half* op = xwh + (size_t)rBase * F + (CT) * 16 + cl; \
        if (rBase + 0 < n) op[0 * F] = __float2half(ACC.x); \
        if (rBase + 1 < n) op[1 * F] = __float2half(ACC.y); \
        if (rBase + 2 < n) op[2 * F] = __float2half(ACC.z); \
        if (rBase + 3 < n) op[3 * F] = __float2half(ACC.w); }
    ST_CT(0, acc0) ST_CT(1, acc1) ST_CT(2, acc2) ST_CT(3, acc3)
#undef ST_CT
}

// xw'[r] = (x[r] @ W) * rsqrt(cnt[r]+1), fp16 (layers 2,3)
__global__ __launch_bounds__(256) void k_gemm(const __half* __restrict__ xh,
                                              const __half* __restrict__ Wt,
                                              const int* __restrict__ cnt,
                                              __half* __restrict__ xwh, int n) {
    int wid = (int)((blockIdx.x * blockDim.x + threadIdx.x) >> 6);
    int lane = threadIdx.x & 63;
    int r0 = wid * 16;
    if (r0 >= n) return;
    int rA = min(r0 + (lane & 15), n - 1);
    int kOff = (lane >> 4) * 8;
    const f16x8* ap = (const f16x8*)(xh + (size_t)rA * F + kOff);
    f16x8 a0 = ap[0];
    f16x8 a1 = ap[4];
    f32x4 acc0, acc1, acc2, acc3;
#define DO_CT(CT, ACC) { \
        const f16x8* bp = (const f16x8*)(Wt + (((CT) * 16 + (lane & 15)) << 6) + kOff); \
        f16x8 b0 = bp[0], b1 = bp[4]; \
        f32x4 c = {0.f, 0.f, 0.f, 0.f}; \
        c = __builtin_amdgcn_mfma_f32_16x16x32_f16(a0, b0, c, 0, 0, 0); \
        c = __builtin_amdgcn_mfma_f32_16x16x32_f16(a1, b1, c, 0, 0, 0); \
        ACC = c; }
    DO_CT(0, acc0) DO_CT(1, acc1) DO_CT(2, acc2) DO_CT(3, acc3)
#undef DO_CT
    int rBase = r0 + ((lane >> 4) << 2);
    int q0 = min(rBase + 0, n - 1), q1 = min(rBase + 1, n - 1);
    int q2 = min(rBase + 2, n - 1), q3 = min(rBase + 3, n - 1);
    float d0 = rsqrtf((float)(cnt[q0] + 1));
    float d1 = rsqrtf((float)(cnt[q1] + 1));
    float d2 = rsqrtf((float)(cnt[q2] + 1));
    float d3 = rsqrtf((float)(cnt[q3] + 1));
    int cl = lane & 15;
#define ST_CT(CT, ACC) { \
        __half* op = xwh + (size_t)rBase * F + (CT) * 16 + cl; \
        if (rBase + 0 < n) op[0 * F] = __float2half(ACC.x * d0); \
        if (rBase + 1 < n) op[1 * F] = __float2half(ACC.y * d1); \
        if (rBase + 2 < n) op[2 * F] = __float2half(ACC.z * d2); \
        if (rBase + 3 < n) op[3 * F] = __float2half(ACC.w * d3); }
    ST_CT(0, acc0) ST_CT(1, acc1) ST_CT(2, acc2) ST_CT(3, acc3)
#undef ST_CT
}

// out[v] = relu( dinv[v] * sum_{r in bucket[v]} (w_r * xw'[r]) + b ), fp16 out
// SCALE_SRC: apply dinv[r]=rsqrt(cnt[r]+1) per edge (layer 1, unscaled xw)
template<bool SCALE_SRC>
__global__ __launch_bounds__(256) void k_gather(const __half* __restrict__ xwh,
                                                const int* __restrict__ meta,
                                                const int* __restrict__ cnt,
                                                const float* __restrict__ bias,
                                                __half* __restrict__ out, int n) {
    int wid = (int)((blockIdx.x * blockDim.x + threadIdx.x) >> 6);
    if (wid >= n) return;
    int lane = threadIdx.x & 63;
    int g = lane >> 4, s = lane & 15;
    int cv = cnt[wid] + 1;               // deg + self
    size_t base = (size_t)wid << 6;
    float ax = 0.0f, ay = 0.0f, az = 0.0f, aw = 0.0f;
    for (int i = g; i < cv; i += 4) {
        int r = meta[base + i];
        uint2 v = *((const uint2*)(xwh + ((size_t)r << 6)) + s);
        __half2 h0 = *reinterpret_cast<const __half2*>(&v.x);
        __half2 h1 = *reinterpret_cast<const __half2*>(&v.y);
        float2 f0 = __half22float2(h0);
        float2 f1 = __half22float2(h1);
        if (SCALE_SRC) {
            float dr = rsqrtf((float)(cnt[r] + 1));
            ax = fmaf(f0.x, dr, ax);
            ay = fmaf(f0.y, dr, ay);
            az = fmaf(f1.x, dr, az);
            aw = fmaf(f1.y, dr, aw);
        } else {
            ax += f0.x; ay += f0.y; az += f1.x; aw += f1.y;
        }
    }
#pragma unroll
    for (int m = 16; m <= 32; m <<= 1) {
        ax += __shfl_xor(ax, m);
        ay += __shfl_xor(ay, m);
        az += __shfl_xor(az, m);
        aw += __shfl_xor(aw, m);
    }
    if (g == 0) {
        float dc = rsqrtf((float)cv);
        float4 bv = ((const float4*)bias)[s];
        __half2 h0 = __floats2half2_rn(fmaxf(fmaf(ax, dc, bv.x), 0.0f),
                                       fmaxf(fmaf(ay, dc, bv.y), 0.0f));
        __half2 h1 = __floats2half2_rn(fmaxf(fmaf(az, dc, bv.z), 0.0f),
                                       fmaxf(fmaf(aw, dc, bv.w), 0.0f));
        __half2* op = (__half2*)(out + ((size_t)wid << 6) + (s << 2));
        op[0] = h0; op[1] = h1;
    }
}

// fused pool over all 3 layer buffers; non-atomic partials [PSPLIT][128][192]
__global__ __launch_bounds__(192) void k_pool(const __half* __restrict__ xA,
                                              const __half* __restrict__ xB,
                                              const __half* __restrict__ xC,
                                              const int* __restrict__ batch, int n,
                                              float* __restrict__ pooledPart) {
    int g = blockIdx.x >> 4, part = blockIdx.x & 15;
    int lo = 0, hi = n;
    while (lo < hi) { int m = (lo + hi) >> 1; if (batch[m] < g) lo = m + 1; else hi = m; }
    int s0 = lo;
    lo = s0; hi = n;
    while (lo < hi) { int m = (lo + hi) >> 1; if (batch[m] < g + 1) lo = m + 1; else hi = m; }
    int e0 = lo;
    int len = e0 - s0;
    int chunk = (len + PSPLIT - 1) / PSPLIT;
    int r0 = s0 + part * chunk;
    int r1 = min(r0 + chunk, e0);
    const __half* src = (threadIdx.x < 64) ? xA : (threadIdx.x < 128) ? xB : xC;
    int f = threadIdx.x & 63;
    float sA = 0.0f, sB = 0.0f;
    int i = r0;
    for (; i + 1 < r1; i += 2) {
        sA += __half2float(src[(size_t)i * F + f]);
        sB += __half2float(src[(size_t)(i + 1) * F + f]);
    }
    if (i < r1) sA += __half2float(src[(size_t)i * F + f]);
    pooledPart[(size_t)(part * NGRAPHS + g) * FCAT + threadIdx.x] = sA + sB;
}

// one block per graph: reduce 16 partials -> pooled (LDS), logits, softmax
__global__ __launch_bounds__(192) void k_head(const float* __restrict__ pooledPart,
                                              const int* __restrict__ batch, int n,
                                              const float* __restrict__ Wf,
                                              const float* __restrict__ bf,
                                              float* __restrict__ out) {
    int g = blockIdx.x;
    __shared__ float pool[FCAT];
    __shared__ float lg[NCLASSES];
    int f = threadIdx.x;
    float s = 0.0f;
#pragma unroll
    for (int p = 0; p < PSPLIT; ++p)
        s += pooledPart[(size_t)(p * NGRAPHS + g) * FCAT + f];
    int lo = 0, hi = n;
    while (lo < hi) { int m = (lo + hi) >> 1; if (batch[m] < g) lo = m + 1; else hi = m; }
    int s0 = lo;
    lo = s0; hi = n;
    while (lo < hi) { int m = (lo + hi) >> 1; if (batch[m] < g + 1) lo = m + 1; else hi = m; }
    float invc = 1.0f / fmaxf((float)(lo - s0), 1.0f);
    pool[f] = s * invc;
    __syncthreads();
    if (f < NCLASSES) {
        float acc = bf[f];
        for (int k = 0; k < FCAT; ++k) acc = fmaf(pool[k], Wf[k * NCLASSES + f], acc);
        lg[f] = acc;
    }
    __syncthreads();
    if (f == 0) {
        float mx = lg[0];
#pragma unroll
        for (int c = 1; c < NCLASSES; ++c) mx = fmaxf(mx, lg[c]);
        float ss = 0.0f;
        float e[NCLASSES];
#pragma unroll
        for (int c = 0; c < NCLASSES; ++c) { e[c] = expf(lg[c] - mx); ss += e[c]; }
        float inv = 1.0f / ss;
#pragma unroll
        for (int c = 0; c < NCLASSES; ++c) out[g * NCLASSES + c] = e[c] * inv;
    }
}

// ---------------------------------------------------------------------------

extern "C" void kernel_launch(void* const* d_in, const int* in_sizes, int n_in,
                              void* d_out, int out_size, void* d_ws, size_t ws_size,
                              hipStream_t stream) {
    const float* features = (const float*)d_in[0];
    const int*   edge     = (const int*)d_in[1];
    const int*   batch    = (const int*)d_in[2];
    const float* W1 = (const float*)d_in[3]; const float* b1 = (const float*)d_in[4];
    const float* W2 = (const float*)d_in[5]; const float* b2 = (const float*)d_in[6];
    const float* W3 = (const float*)d_in[7]; const float* b3 = (const float*)d_in[8];
    const float* Wf = (const float*)d_in[9]; const float* bf = (const float*)d_in[10];
    float* out = (float*)d_out;

    const int n = in_sizes[0] / F;   // 100000
    const int E = in_sizes[1] / 2;   // 1600000
    const int* row = edge;
    const int* col = edge + E;

    // workspace layout
    __half* x0h   = (__half*)d_ws;                     // [n*64] layer3 out
    __half* bufAh = x0h + (size_t)n * F;               // [n*64] layer1 out
    __half* bufBh = bufAh + (size_t)n * F;             // [n*64] layer2 out
    __half* xwh   = bufBh + (size_t)n * F;             // [n*64]
    __half* Wt    = xwh + (size_t)n * F;               // [3*64*64]
    int*    meta  = (int*)(Wt + 3 * F * F);            // [n*CAP]
    int*    slot  = meta + (size_t)n * CAP;            // [E]
    int*    cnt   = slot + E;                          // [n]
    float*  pooledPart = (float*)(cnt + n);            // [16*128*192]

    const int BT = 256;
    const int EA = (E / 2 + 255) & ~255;   // chunk A size (aligned)
    const int EB = E - EA;                 // chunk B size
    int cA = (EA + BT - 1) / BT;           // count/fill blocks for A
    int cB = (EB + BT - 1) / BT;           // count/fill blocks for B
    int gW  = (n + 3) / 4;                 // gather grid (4 nodes/block)
    int gT  = ((n + 15) / 16 + 3) / 4;     // gemm grid (4 tiles/block)

    // ---- prep (cnt=0, self meta, Wt) ----
    k_prep<<<256, BT, 0, stream>>>(W1, W2, W3, cnt, meta, Wt, n);
    // ---- D1: count(A) ∥ layer-1 GEMM (fp32 direct, unscaled) ----
    k_build<<<gT + cA, BT, 0, stream>>>(row, col, slot, cnt, meta, features, Wt,
                                        xwh, n, gT, 0, EA, 0, 0);
    // ---- D2: count(B) ∥ fill(A) ----
    k_build<<<cB + cA, BT, 0, stream>>>(row, col, slot, cnt, meta, features, Wt,
                                        xwh, n, 0, EA, EB, 0, EA);
    // ---- D3: fill(B) ----
    k_build<<<cB, BT, 0, stream>>>(row, col, slot, cnt, meta, features, Wt,
                                   xwh, n, 0, 0, 0, EA, EB);

    // ---- layer 1 gather (per-edge dinv) ----
    k_gather<true><<<gW, BT, 0, stream>>>(xwh, meta, cnt, b1, bufAh, n);

    // ---- layer 2 ----
    k_gemm<<<gT, BT, 0, stream>>>(bufAh, Wt + 4096, cnt, xwh, n);
    k_gather<false><<<gW, BT, 0, stream>>>(xwh, meta, cnt, b2, bufBh, n);

    // ---- layer 3 ----
    k_gemm<<<gT, BT, 0, stream>>>(bufBh, Wt + 8192, cnt, xwh, n);
    k_gather<false><<<gW, BT, 0, stream>>>(xwh, meta, cnt, b3, x0h, n);

    // ---- fused pool (all 3 layers) + head ----
    k_pool<<<NGRAPHS * PSPLIT, FCAT, 0, stream>>>(bufAh, bufBh, x0h, batch, n, pooledPart);
    k_head<<<NGRAPHS, FCAT, 0, stream>>>(pooledPart, batch, n, Wf, bf, out);
}

// Round 13
// 318.490 us; speedup vs baseline: 1.1119x; 1.1119x over previous
//
#include <hip/hip_runtime.h>
#include <hip/hip_bf16.h>
#include <hip/hip_fp16.h>
#include <math.h>

// ---------------------------------------------------------------------------
// GCN 3-layer + mean-pool + linear head + softmax, fp32 in/out.
// Padded-bucket adjacency (64 slots/node, self-loop slot 0), chunk-pipelined
// counting sort:
//   D1: count(A) ∥ layer-1 GEMM (fp32 features direct, unscaled)
//   D2: count(B) ∥ fill(A)
//   D3: fill(B) ∥ scale xwh by rsqrt(cnt+1)   [cnt final after D2]
// Gathers are scale-free: bucket meta hoisted to registers (one coalesced
// load + __shfl), xwh row loads fully pipelined. fp16 pipeline, MFMA.
// ---------------------------------------------------------------------------

#define F 64
#define NGRAPHS 128
#define NCLASSES 10
#define FCAT 192
#define PSPLIT 16
#define CAP 64            // slots per node (deg+1; Poisson(16) -> safe)

typedef _Float16 f16x8 __attribute__((ext_vector_type(8)));
typedef float f32x4 __attribute__((ext_vector_type(4)));

// ---- prep: cnt=0, self-loop meta, W->Wt fp16 transposed -------------------
__global__ void k_prep(const float* __restrict__ W1, const float* __restrict__ W2,
                       const float* __restrict__ W3,
                       int* __restrict__ cnt, int* __restrict__ meta,
                       __half* __restrict__ Wt, int n) {
    int tid = blockIdx.x * blockDim.x + threadIdx.x;
    int stride = gridDim.x * blockDim.x;
    for (int i = tid; i < n; i += stride) {
        cnt[i] = 0;
        meta[(size_t)i << 6] = i;          // self-loop at slot 0
    }
    for (int t = tid; t < 3 * 4096; t += stride) {
        int w = t >> 12, idx = t & 4095;
        int c = idx >> 6, k = idx & 63;
        const float* W = (w == 0) ? W1 : (w == 1) ? W2 : W3;
        Wt[t] = __float2half(W[k * F + c]);
    }
}

// ---- build: [0,gemmBlocks) layer-1 GEMM; [.,+cntBlocks) count; then fill;
//             then scale xwh (in-place * rsqrt(cnt+1), 16B per thread) -------
__global__ __launch_bounds__(256) void k_build(
        const int* __restrict__ row, const int* __restrict__ col,
        int* __restrict__ slot, int* __restrict__ cnt, int* __restrict__ meta,
        const float* __restrict__ features, const __half* __restrict__ Wt,
        __half* __restrict__ xwh, int n,
        int gemmBlocks, int cntStart, int cntCount, int fillStart, int fillCount,
        int scaleOn) {
    int b = blockIdx.x;
    if (b >= gemmBlocks) {
        b -= gemmBlocks;
        int cntBlocks = (cntCount + 255) >> 8;
        int fillBlocks = (fillCount + 255) >> 8;
        if (b < cntBlocks) {
            int e = b * 256 + threadIdx.x;
            if (e < cntCount) {
                e += cntStart;
                slot[e] = atomicAdd(&cnt[col[e]], 1);
            }
        } else if (b < cntBlocks + fillBlocks) {
            int e = (b - cntBlocks) * 256 + threadIdx.x;
            if (e < fillCount) {
                e += fillStart;
                meta[((size_t)col[e] << 6) + 1 + slot[e]] = row[e];
            }
        } else if (scaleOn) {
            int t = (b - cntBlocks - fillBlocks) * 256 + threadIdx.x;
            if (t < n * 8) {                       // 8 x 16B per row
                int r = t >> 3;
                float d = rsqrtf((float)(cnt[r] + 1));
                uint4* p = (uint4*)xwh + t;
                uint4 v = *p;
                __half2* h = (__half2*)&v;
#pragma unroll
                for (int q = 0; q < 4; ++q) {
                    float2 f = __half22float2(h[q]);
                    h[q] = __floats2half2_rn(f.x * d, f.y * d);
                }
                *p = v;
            }
        }
        return;
    }
    // ---- layer-1 GEMM tile (16 rows), fp32 features -> fp16 frags ----
    int wid = (int)((b * 256 + threadIdx.x) >> 6);
    int lane = threadIdx.x & 63;
    int r0 = wid * 16;
    if (r0 >= n) return;
    int rA = min(r0 + (lane & 15), n - 1);
    int kOff = (lane >> 4) * 8;
    const float4* xp = (const float4*)(features + (size_t)rA * F + kOff);
    float4 fa = xp[0], fb = xp[1];
    float4 fc = xp[8], fd = xp[9];
    f16x8 a0 = {(_Float16)fa.x, (_Float16)fa.y, (_Float16)fa.z, (_Float16)fa.w,
                (_Float16)fb.x, (_Float16)fb.y, (_Float16)fb.z, (_Float16)fb.w};
    f16x8 a1 = {(_Float16)fc.x, (_Float16)fc.y, (_Float16)fc.z, (_Float16)fc.w,
                (_Float16)fd.x, (_Float16)fd.y, (_Float16)fd.z, (_Float16)fd.w};
    f32x4 acc0, acc1, acc2, acc3;
#define DO_CT(CT, ACC) { \
        const f16x8* bp = (const f16x8*)(Wt + (((CT) * 16 + (lane & 15)) << 6) + kOff); \
        f16x8 b0 = bp[0], b1 = bp[4]; \
        f32x4 c = {0.f, 0.f, 0.f, 0.f}; \
        c = __builtin_amdgcn_mfma_f32_16x16x32_f16(a0, b0, c, 0, 0, 0); \
        c = __builtin_amdgcn_mfma_f32_16x16x32_f16(a1, b1, c, 0, 0, 0); \
        ACC = c; }
    DO_CT(0, acc0) DO_CT(1, acc1) DO_CT(2, acc2) DO_CT(3, acc3)
#undef DO_CT
    int rBase = r0 + ((lane >> 4) << 2);
    int cl = lane & 15;
#define ST_CT(CT, ACC) { \
        __half* op = xwh + (size_t)rBase * F + (CT) * 16 + cl; \
        if (rBase + 0 < n) op[0 * F] = __float2half(ACC.x); \
        if (rBase + 1 < n) op[1 * F] = __float2half(ACC.y); \
        if (rBase + 2 < n) op[2 * F] = __float2half(ACC.z); \
        if (rBase + 3 < n) op[3 * F] = __float2half(ACC.w); }
    ST_CT(0, acc0) ST_CT(1, acc1) ST_CT(2, acc2) ST_CT(3, acc3)
#undef ST_CT
}

// xw'[r] = (x[r] @ W) * rsqrt(cnt[r]+1), fp16 (layers 2,3)
__global__ __launch_bounds__(256) void k_gemm(const __half* __restrict__ xh,
                                              const __half* __restrict__ Wt,
                                              const int* __restrict__ cnt,
                                              __half* __restrict__ xwh, int n) {
    int wid = (int)((blockIdx.x * blockDim.x + threadIdx.x) >> 6);
    int lane = threadIdx.x & 63;
    int r0 = wid * 16;
    if (r0 >= n) return;
    int rA = min(r0 + (lane & 15), n - 1);
    int kOff = (lane >> 4) * 8;
    const f16x8* ap = (const f16x8*)(xh + (size_t)rA * F + kOff);
    f16x8 a0 = ap[0];
    f16x8 a1 = ap[4];
    f32x4 acc0, acc1, acc2, acc3;
#define DO_CT(CT, ACC) { \
        const f16x8* bp = (const f16x8*)(Wt + (((CT) * 16 + (lane & 15)) << 6) + kOff); \
        f16x8 b0 = bp[0], b1 = bp[4]; \
        f32x4 c = {0.f, 0.f, 0.f, 0.f}; \
        c = __builtin_amdgcn_mfma_f32_16x16x32_f16(a0, b0, c, 0, 0, 0); \
        c = __builtin_amdgcn_mfma_f32_16x16x32_f16(a1, b1, c, 0, 0, 0); \
        ACC = c; }
    DO_CT(0, acc0) DO_CT(1, acc1) DO_CT(2, acc2) DO_CT(3, acc3)
#undef DO_CT
    int rBase = r0 + ((lane >> 4) << 2);
    int q0 = min(rBase + 0, n - 1), q1 = min(rBase + 1, n - 1);
    int q2 = min(rBase + 2, n - 1), q3 = min(rBase + 3, n - 1);
    float d0 = rsqrtf((float)(cnt[q0] + 1));
    float d1 = rsqrtf((float)(cnt[q1] + 1));
    float d2 = rsqrtf((float)(cnt[q2] + 1));
    float d3 = rsqrtf((float)(cnt[q3] + 1));
    int cl = lane & 15;
#define ST_CT(CT, ACC) { \
        __half* op = xwh + (size_t)rBase * F + (CT) * 16 + cl; \
        if (rBase + 0 < n) op[0 * F] = __float2half(ACC.x * d0); \
        if (rBase + 1 < n) op[1 * F] = __float2half(ACC.y * d1); \
        if (rBase + 2 < n) op[2 * F] = __float2half(ACC.z * d2); \
        if (rBase + 3 < n) op[3 * F] = __float2half(ACC.w * d3); }
    ST_CT(0, acc0) ST_CT(1, acc1) ST_CT(2, acc2) ST_CT(3, acc3)
#undef ST_CT
}

// out[v] = relu( dinv[v] * sum_{r in bucket[v]} xw'[r] + b ), fp16 out.
// Bucket meta hoisted to registers (1 coalesced load), r via __shfl ->
// xwh row loads are independent and pipeline.
__global__ __launch_bounds__(256) void k_gather(const __half* __restrict__ xwh,
                                                const int* __restrict__ meta,
                                                const int* __restrict__ cnt,
                                                const float* __restrict__ bias,
                                                __half* __restrict__ out, int n) {
    int wid = (int)((blockIdx.x * blockDim.x + threadIdx.x) >> 6);
    if (wid >= n) return;
    int lane = threadIdx.x & 63;
    int g = lane >> 4, s = lane & 15;
    int cv = cnt[wid] + 1;               // deg + self
    size_t base = (size_t)wid << 6;
    int myMeta = meta[base + (lane < cv ? lane : 0)];
    float ax = 0.0f, ay = 0.0f, az = 0.0f, aw = 0.0f;
    for (int i = g; i < cv; i += 4) {
        int r = __shfl(myMeta, i);
        uint2 v = *((const uint2*)(xwh + ((size_t)r << 6)) + s);
        __half2 h0 = *reinterpret_cast<const __half2*>(&v.x);
        __half2 h1 = *reinterpret_cast<const __half2*>(&v.y);
        float2 f0 = __half22float2(h0);
        float2 f1 = __half22float2(h1);
        ax += f0.x; ay += f0.y; az += f1.x; aw += f1.y;
    }
#pragma unroll
    for (int m = 16; m <= 32; m <<= 1) {
        ax += __shfl_xor(ax, m);
        ay += __shfl_xor(ay, m);
        az += __shfl_xor(az, m);
        aw += __shfl_xor(aw, m);
    }
    if (g == 0) {
        float dc = rsqrtf((float)cv);
        float4 bv = ((const float4*)bias)[s];
        __half2 h0 = __floats2half2_rn(fmaxf(fmaf(ax, dc, bv.x), 0.0f),
                                       fmaxf(fmaf(ay, dc, bv.y), 0.0f));
        __half2 h1 = __floats2half2_rn(fmaxf(fmaf(az, dc, bv.z), 0.0f),
                                       fmaxf(fmaf(aw, dc, bv.w), 0.0f));
        __half2* op = (__half2*)(out + ((size_t)wid << 6) + (s << 2));
        op[0] = h0; op[1] = h1;
    }
}

// fused pool over all 3 layer buffers; non-atomic partials [PSPLIT][128][192]
__global__ __launch_bounds__(192) void k_pool(const __half* __restrict__ xA,
                                              const __half* __restrict__ xB,
                                              const __half* __restrict__ xC,
                                              const int* __restrict__ batch, int n,
                                              float* __restrict__ pooledPart) {
    int g = blockIdx.x >> 4, part = blockIdx.x & 15;
    int lo = 0, hi = n;
    while (lo < hi) { int m = (lo + hi) >> 1; if (batch[m] < g) lo = m + 1; else hi = m; }
    int s0 = lo;
    lo = s0; hi = n;
    while (lo < hi) { int m = (lo + hi) >> 1; if (batch[m] < g + 1) lo = m + 1; else hi = m; }
    int e0 = lo;
    int len = e0 - s0;
    int chunk = (len + PSPLIT - 1) / PSPLIT;
    int r0 = s0 + part * chunk;
    int r1 = min(r0 + chunk, e0);
    const __half* src = (threadIdx.x < 64) ? xA : (threadIdx.x < 128) ? xB : xC;
    int f = threadIdx.x & 63;
    float sA = 0.0f, sB = 0.0f;
    int i = r0;
    for (; i + 1 < r1; i += 2) {
        sA += __half2float(src[(size_t)i * F + f]);
        sB += __half2float(src[(size_t)(i + 1) * F + f]);
    }
    if (i < r1) sA += __half2float(src[(size_t)i * F + f]);
    pooledPart[(size_t)(part * NGRAPHS + g) * FCAT + threadIdx.x] = sA + sB;
}

// one block per graph: reduce 16 partials -> pooled (LDS), logits, softmax
__global__ __launch_bounds__(192) void k_head(const float* __restrict__ pooledPart,
                                              const int* __restrict__ batch, int n,
                                              const float* __restrict__ Wf,
                                              const float* __restrict__ bf,
                                              float* __restrict__ out) {
    int g = blockIdx.x;
    __shared__ float pool[FCAT];
    __shared__ float lg[NCLASSES];
    int f = threadIdx.x;
    float s = 0.0f;
#pragma unroll
    for (int p = 0; p < PSPLIT; ++p)
        s += pooledPart[(size_t)(p * NGRAPHS + g) * FCAT + f];
    int lo = 0, hi = n;
    while (lo < hi) { int m = (lo + hi) >> 1; if (batch[m] < g) lo = m + 1; else hi = m; }
    int s0 = lo;
    lo = s0; hi = n;
    while (lo < hi) { int m = (lo + hi) >> 1; if (batch[m] < g + 1) lo = m + 1; else hi = m; }
    float invc = 1.0f / fmaxf((float)(lo - s0), 1.0f);
    pool[f] = s * invc;
    __syncthreads();
    if (f < NCLASSES) {
        float acc = bf[f];
        for (int k = 0; k < FCAT; ++k) acc = fmaf(pool[k], Wf[k * NCLASSES + f], acc);
        lg[f] = acc;
    }
    __syncthreads();
    if (f == 0) {
        float mx = lg[0];
#pragma unroll
        for (int c = 1; c < NCLASSES; ++c) mx = fmaxf(mx, lg[c]);
        float ss = 0.0f;
        float e[NCLASSES];
#pragma unroll
        for (int c = 0; c < NCLASSES; ++c) { e[c] = expf(lg[c] - mx); ss += e[c]; }
        float inv = 1.0f / ss;
#pragma unroll
        for (int c = 0; c < NCLASSES; ++c) out[g * NCLASSES + c] = e[c] * inv;
    }
}

// ---------------------------------------------------------------------------

extern "C" void kernel_launch(void* const* d_in, const int* in_sizes, int n_in,
                              void* d_out, int out_size, void* d_ws, size_t ws_size,
                              hipStream_t stream) {
    const float* features = (const float*)d_in[0];
    const int*   edge     = (const int*)d_in[1];
    const int*   batch    = (const int*)d_in[2];
    const float* W1 = (const float*)d_in[3]; const float* b1 = (const float*)d_in[4];
    const float* W2 = (const float*)d_in[5]; const float* b2 = (const float*)d_in[6];
    const float* W3 = (const float*)d_in[7]; const float* b3 = (const float*)d_in[8];
    const float* Wf = (const float*)d_in[9]; const float* bf = (const float*)d_in[10];
    float* out = (float*)d_out;

    const int n = in_sizes[0] / F;   // 100000
    const int E = in_sizes[1] / 2;   // 1600000
    const int* row = edge;
    const int* col = edge + E;

    // workspace layout
    __half* x0h   = (__half*)d_ws;                     // [n*64] layer3 out
    __half* bufAh = x0h + (size_t)n * F;               // [n*64] layer1 out
    __half* bufBh = bufAh + (size_t)n * F;             // [n*64] layer2 out
    __half* xwh   = bufBh + (size_t)n * F;             // [n*64]
    __half* Wt    = xwh + (size_t)n * F;               // [3*64*64]
    int*    meta  = (int*)(Wt + 3 * F * F);            // [n*CAP]
    int*    slot  = meta + (size_t)n * CAP;            // [E]
    int*    cnt   = slot + E;                          // [n]
    float*  pooledPart = (float*)(cnt + n);            // [16*128*192]

    const int BT = 256;
    const int EA = (E / 2 + 255) & ~255;   // chunk A size (aligned)
    const int EB = E - EA;                 // chunk B size
    int cA = (EA + BT - 1) / BT;
    int cB = (EB + BT - 1) / BT;
    int sBlk = (n * 8 + BT - 1) / BT;      // scale blocks (16B/thread)
    int gW  = (n + 3) / 4;                 // gather grid (4 nodes/block)
    int gT  = ((n + 15) / 16 + 3) / 4;     // gemm grid (4 tiles/block)

    // ---- prep (cnt=0, self meta, Wt) ----
    k_prep<<<256, BT, 0, stream>>>(W1, W2, W3, cnt, meta, Wt, n);
    // ---- D1: count(A) ∥ layer-1 GEMM (fp32 direct, unscaled) ----
    k_build<<<gT + cA, BT, 0, stream>>>(row, col, slot, cnt, meta, features, Wt,
                                        xwh, n, gT, 0, EA, 0, 0, 0);
    // ---- D2: count(B) ∥ fill(A) ----
    k_build<<<cA + cB, BT, 0, stream>>>(row, col, slot, cnt, meta, features, Wt,
                                        xwh, n, 0, EA, EB, 0, EA, 0);
    // ---- D3: fill(B) ∥ scale xwh ----
    k_build<<<cB + sBlk, BT, 0, stream>>>(row, col, slot, cnt, meta, features, Wt,
                                          xwh, n, 0, 0, 0, EA, EB, 1);

    // ---- layer 1 gather ----
    k_gather<<<gW, BT, 0, stream>>>(xwh, meta, cnt, b1, bufAh, n);

    // ---- layer 2 ----
    k_gemm<<<gT, BT, 0, stream>>>(bufAh, Wt + 4096, cnt, xwh, n);
    k_gather<<<gW, BT, 0, stream>>>(xwh, meta, cnt, b2, bufBh, n);

    // ---- layer 3 ----
    k_gemm<<<gT, BT, 0, stream>>>(bufBh, Wt + 8192, cnt, xwh, n);
    k_gather<<<gW, BT, 0, stream>>>(xwh, meta, cnt, b3, x0h, n);

    // ---- fused pool (all 3 layers) + head ----
    k_pool<<<NGRAPHS * PSPLIT, FCAT, 0, stream>>>(bufAh, bufBh, x0h, batch, n, pooledPart);
    k_head<<<NGRAPHS, FCAT, 0, stream>>>(pooledPart, batch, n, Wf, bf, out);
}